// Round 6
// baseline (203.896 us; speedup 1.0000x reference)
//
#include <hip/hip_runtime.h>
#include <hip/hip_bf16.h>

typedef _Float16 f16x8 __attribute__((ext_vector_type(8)));
typedef _Float16 f16x4 __attribute__((ext_vector_type(4)));
typedef float f32x4 __attribute__((ext_vector_type(4)));

__device__ __forceinline__ void async_ld16(_Float16* lds, const _Float16* g) {
    __builtin_amdgcn_global_load_lds(
        (const __attribute__((address_space(1))) void*)g,
        (__attribute__((address_space(3))) void*)lds, 16, 0, 0);
}

#define VMCNT(n) asm volatile("s_waitcnt vmcnt(" #n ")" ::: "memory")
#define BAR() __builtin_amdgcn_s_barrier()

// ============================================================================
// 256x256-tile 8-phase pipelined GEMM:  C[M,N] = A[M,K] * B[N,K]^T (f16->f32)
// 8 waves (2M x 4N), per-wave 128x64, fragment map (R4/R5-verified):
//   row = ms*128 + m*32 + wm*16 + (quad*4+e),  col = ns*128 + nn*64 + wn*16 + l16
// BK=64, LDS 128 KB, XOR chunk swizzle (R5-verified: 0 bank conflicts).
// R6 change (schedule-only): READ-AHEAD. Every ds_read is issued >=1 full
// MFMA phase before its consuming wait (was bunched 12/4/8/0 with lgkmcnt(0)
// right after -> ~500cyc LDS bubble per K-tile):
//   - end of ph4 (post-vmcnt(6) = the moment buf[t+1] is fully landed):
//     read alo,blo for t+1
//   - ph1 reads bhi (used ph2/3); ph2 reads ahi (used ph3/4)
// No explicit lgkmcnt: compiler inserts counted waits at MFMA use sites.
// Barrier/STAGE/vmcnt skeleton identical to R5 (green). Hazard windows:
// each read's consuming wait + phase closing BAR precede the next STAGE
// into that half-tile (ledger re-traced per half-tile).
// ============================================================================
__global__ __launch_bounds__(512, 2) void gemm_bt256(
    const _Float16* __restrict__ A,
    const _Float16* __restrict__ B,
    float* __restrict__ C,
    int M, int N, int K, int Ks)
{
    __shared__ _Float16 Asm[2][256 * 64];
    __shared__ _Float16 Bsm[2][256 * 64];

    const int tid  = threadIdx.x;
    const int w    = tid >> 6;       // wave 0..7
    const int lane = tid & 63;
    const int l16  = lane & 15;
    const int quad = lane >> 4;
    const int wm   = w >> 2;         // 0..1  (M-group)
    const int wn   = w & 3;          // 0..3  (N-group)

    // ---- bijective XCD-chunked block remap (m204) ---------------------------
    const int gx = gridDim.x, gy = gridDim.y;
    const int total = gx * gy * (int)gridDim.z;
    int lid = (int)blockIdx.x + gx * ((int)blockIdx.y + gy * (int)blockIdx.z);
    {
        const int q = total >> 3, r = total & 7;
        const int xcd = lid & 7, i = lid >> 3;
        lid = (xcd < r ? xcd * (q + 1) : r * (q + 1) + (xcd - r) * q) + i;
    }
    const int bx = lid % gx;
    const int by = (lid / gx) % gy;
    const int bz = lid / (gx * gy);

    const int row0 = by * 256;
    const int col0 = bx * 256;

    const _Float16* Ab = A + (size_t)row0 * K + (size_t)bz * Ks;
    const _Float16* Bb = B + (size_t)col0 * K + (size_t)bz * Ks;

    // ---- staging addressing -------------------------------------------------
    // Half-tile = 128 rows x 64 halfs = 16 KB = 2 gload_lds per wave.
    // LDS dest linear: lane l -> row w*16 + (l>>3), chunk l&7.
    // Global source chunk pre-swizzled: lc = (l&7) ^ (row&7).
    const int lr = lane >> 3;
    const int lc = (lane & 7) ^ lr;
    const size_t soff  = (size_t)(w * 16 + lr) * K + lc * 8;
    const _Float16* pa = Ab + soff;
    const _Float16* pb = Bb + soff;
    const size_t jstep = (size_t)8 * K;    // +8 rows
    const size_t hstep = (size_t)128 * K;  // +1 half-tile

    auto STAGE = [&](_Float16* sm, const _Float16* gsrc, int h, int kcol) {
        _Float16* d = sm + h * 8192 + w * 1024;
        const _Float16* s = gsrc + (size_t)h * hstep + kcol;
        async_ld16(d,       s);
        async_ld16(d + 512, s + jstep);
    };

    // ---- fragment-read addressing (swizzled) --------------------------------
    // row&7 == l16&7; k-slice ks chunk = (ks*4+quad) ^ (row&7).
    const int abase = (wm * 16 + l16) * 64;
    const int bbase = (wn * 16 + l16) * 64;
    const int rs0   = ((quad)     ^ (l16 & 7)) * 8;   // k-slice 0
    const int rs1   = ((4 + quad) ^ (l16 & 7)) * 8;   // k-slice 1

#define READ_A(dst, bufp, msoff)                                               \
    _Pragma("unroll")                                                          \
    for (int m_ = 0; m_ < 4; ++m_) {                                           \
        dst[m_][0] = *(const f16x8*)((bufp) + (msoff) + m_ * 2048 + abase + rs0);\
        dst[m_][1] = *(const f16x8*)((bufp) + (msoff) + m_ * 2048 + abase + rs1);\
    }
#define READ_B(dst, bufp, nsoff)                                               \
    _Pragma("unroll")                                                          \
    for (int n_ = 0; n_ < 2; ++n_) {                                           \
        dst[n_][0] = *(const f16x8*)((bufp) + (nsoff) + n_ * 4096 + bbase + rs0);\
        dst[n_][1] = *(const f16x8*)((bufp) + (nsoff) + n_ * 4096 + bbase + rs1);\
    }
#define MFMA4x2(accrow, afrag, bfrag, bcol)                                    \
    _Pragma("unroll")                                                          \
    for (int m_ = 0; m_ < 4; ++m_)                                             \
      _Pragma("unroll")                                                        \
      for (int n_ = 0; n_ < 2; ++n_) {                                         \
        acc[(accrow) + m_][(bcol) + n_] =                                      \
            __builtin_amdgcn_mfma_f32_16x16x32_f16(                            \
                afrag[m_][0], bfrag[n_][0], acc[(accrow) + m_][(bcol) + n_],   \
                0, 0, 0);                                                      \
        acc[(accrow) + m_][(bcol) + n_] =                                      \
            __builtin_amdgcn_mfma_f32_16x16x32_f16(                            \
                afrag[m_][1], bfrag[n_][1], acc[(accrow) + m_][(bcol) + n_],   \
                0, 0, 0);                                                      \
      }

    f32x4 acc[8][4] = {};
    const int NT = Ks >> 6;   // K-tiles of 64

    // ---- prologue: kt0 fully + first 3 half-tiles of kt1 --------------------
    STAGE(&Asm[0][0], pa, 0, 0);
    STAGE(&Bsm[0][0], pb, 0, 0);
    STAGE(&Bsm[0][0], pb, 1, 0);
    STAGE(&Asm[0][0], pa, 1, 0);
    if (NT > 1) {
        STAGE(&Asm[1][0], pa, 0, 64);
        STAGE(&Bsm[1][0], pb, 0, 64);
        STAGE(&Bsm[1][0], pb, 1, 64);
        VMCNT(6);              // oldest 8 loads (= all of kt0) landed
    } else {
        VMCNT(0);
    }
    BAR();

    f16x8 alo[4][2], ahi[4][2], blo[2][2], bhi[2][2];
    // pre-read Q1 operands of kt0 (sources landed above)
    READ_A(alo, &Asm[0][0], 0);
    READ_B(blo, &Bsm[0][0], 0);

    for (int t = 0; t < NT; ++t) {
        const int buf = t & 1;
        const _Float16* abuf = &Asm[buf][0];
        const _Float16* bbuf = &Bsm[buf][0];
        _Float16* const acur = &Asm[buf][0];        // kt t+2 lands here
        _Float16* const bcur = &Bsm[buf][0];
        _Float16* const anxt = &Asm[buf ^ 1][0];    // kt t+1 A.h1

        // ---- phase 1: MFMA Q1 (ms=0,ns=0) on pre-read alo,blo;
        //      read-ahead bhi (B.h1[t], landed since vmcnt of t-1) -----------
        READ_B(bhi, bbuf, 8192);
        if (t + 1 < NT) STAGE(anxt, pa, 1, (t + 1) * 64);
        BAR();
        __builtin_amdgcn_s_setprio(1);
        MFMA4x2(0, alo, blo, 0);
        __builtin_amdgcn_s_setprio(0);
        BAR();

        // ---- phase 2: MFMA Q2 (ms=0,ns=1) on alo,bhi; read-ahead ahi -------
        READ_A(ahi, abuf, 8192);
        if (t + 2 < NT) STAGE(acur, pa, 0, (t + 2) * 64);
        BAR();
        __builtin_amdgcn_s_setprio(1);
        MFMA4x2(0, alo, bhi, 2);
        __builtin_amdgcn_s_setprio(0);
        BAR();

        // ---- phase 3: MFMA Q3 (ms=1,ns=1) on ahi,bhi -----------------------
        if (t + 2 < NT) STAGE(bcur, pb, 0, (t + 2) * 64);
        BAR();
        __builtin_amdgcn_s_setprio(1);
        MFMA4x2(4, ahi, bhi, 2);
        __builtin_amdgcn_s_setprio(0);
        BAR();

        // ---- phase 4: MFMA Q4 (ms=1,ns=0) on ahi,blo; vmcnt(6) retires all
        //      of kt t+1 -> immediately pre-read alo,blo for t+1 -------------
        if (t + 2 < NT) STAGE(bcur, pb, 1, (t + 2) * 64);
        BAR();
        __builtin_amdgcn_s_setprio(1);
        MFMA4x2(4, ahi, blo, 0);
        __builtin_amdgcn_s_setprio(0);
        if (t + 2 < NT) { VMCNT(6); } else { VMCNT(0); }
        if (t + 1 < NT) {
            const _Float16* nab = &Asm[buf ^ 1][0];
            const _Float16* nbb = &Bsm[buf ^ 1][0];
            READ_A(alo, nab, 0);
            READ_B(blo, nbb, 0);
        }
        BAR();
    }

    // ---- epilogue: C/D layout col = l16, row = quad*4 + reg ----------------
    float* Cb = C + (size_t)bz * ((size_t)M * N);
    #pragma unroll
    for (int i = 0; i < 8; ++i) {
        const int ms = i >> 2, m = i & 3;
        const int gr = row0 + ms * 128 + m * 32 + wm * 16 + quad * 4;
        #pragma unroll
        for (int j = 0; j < 4; ++j) {
            const int ns = j >> 1, nn = j & 1;
            const int gc = col0 + ns * 128 + nn * 64 + wn * 16 + l16;
            const f32x4 v = acc[i][j];
            #pragma unroll
            for (int e = 0; e < 4; ++e)
                Cb[(size_t)(gr + e) * N + gc] = v[e];
        }
    }
#undef READ_A
#undef READ_B
#undef MFMA4x2
}

// ============================================================================
// Fallback 128x128 GEMM (verified passing) for tiny-workspace nc=128 path.
// ============================================================================
__global__ __launch_bounds__(256) void gemm_bt(
    const _Float16* __restrict__ A,
    const _Float16* __restrict__ B,
    float* __restrict__ C,
    int M, int N, int K, int Ks)
{
    __shared__ _Float16 At[2][128 * 32];
    __shared__ _Float16 Bt[2][128 * 32];

    const int tid  = threadIdx.x;
    const int wave = tid >> 6;
    const int lane = tid & 63;

    int gx = gridDim.x, gy = gridDim.y;
    int bx = blockIdx.x, by = blockIdx.y;
    if (((gx & 7) == 0) && ((gy & 7) == 0)) {
        const int bid    = bx + gx * by;
        const int ntx    = gx >> 3;
        const int sid    = bid >> 6;
        const int within = bid & 63;
        const int sx = sid % ntx;
        const int sy = sid / ntx;
        bx = (sx << 3) + (within & 7);
        by = (sy << 3) + (within >> 3);
    }
    const int row0 = by * 128;
    const int col0 = bx * 128;

    const int wr = (wave >> 1) * 64;
    const int wc = (wave & 1) * 64;
    const int quad = lane >> 4;
    const int l16  = lane & 15;

    f32x4 acc[4][4] = {};

    const int srow  = lane >> 2;
    const int skoff = (lane & 3) * 8;
    const size_t K64 = (size_t)64 * K;

    const _Float16* Ab = A + (size_t)row0 * K + (size_t)blockIdx.z * Ks;
    const _Float16* Bb = B + (size_t)col0 * K + (size_t)blockIdx.z * Ks;
    float* Cb = C + (size_t)blockIdx.z * M * N;

    const _Float16* pa = Ab + (size_t)(wave * 16 + srow) * K + skoff;
    const _Float16* pb = Bb + (size_t)(wave * 16 + srow) * K + skoff;

    async_ld16(At[0] + wave * 512,       pa);
    async_ld16(At[0] + (wave + 4) * 512, pa + K64);
    async_ld16(Bt[0] + wave * 512,       pb);
    async_ld16(Bt[0] + (wave + 4) * 512, pb + K64);
    __syncthreads();

    int cur = 0;
    for (int k0 = 0; k0 < Ks; k0 += 32) {
        const int nxt = cur ^ 1;
        if (k0 + 32 < Ks) {
            const _Float16* qa = pa + k0 + 32;
            const _Float16* qb = pb + k0 + 32;
            async_ld16(At[nxt] + wave * 512,       qa);
            async_ld16(At[nxt] + (wave + 4) * 512, qa + K64);
            async_ld16(Bt[nxt] + wave * 512,       qb);
            async_ld16(Bt[nxt] + (wave + 4) * 512, qb + K64);
        }

        f16x8 af[4], bf[4];
        #pragma unroll
        for (int r = 0; r < 4; ++r)
            af[r] = *(const f16x8*)&At[cur][(wr + r * 16 + l16) * 32 + quad * 8];
        #pragma unroll
        for (int c = 0; c < 4; ++c)
            bf[c] = *(const f16x8*)&Bt[cur][(wc + c * 16 + l16) * 32 + quad * 8];

        #pragma unroll
        for (int r = 0; r < 4; ++r)
            #pragma unroll
            for (int c = 0; c < 4; ++c)
                acc[r][c] = __builtin_amdgcn_mfma_f32_16x16x32_f16(af[r], bf[c], acc[r][c], 0, 0, 0);

        __syncthreads();
        cur = nxt;
    }

    #pragma unroll
    for (int r = 0; r < 4; ++r) {
        const int growb = row0 + wr + r * 16 + quad * 4;
        #pragma unroll
        for (int c = 0; c < 4; ++c) {
            const int gcol = col0 + wc + c * 16 + l16;
            #pragma unroll
            for (int i = 0; i < 4; ++i)
                Cb[(size_t)(growb + i) * N + gcol] = acc[r][c][i];
        }
    }
}

// one block (256 thr) per row of S [rows x 4096]; P = softmax(S)*scale in fp16
__global__ __launch_bounds__(256) void softmax_rows(
    const float* __restrict__ S, _Float16* __restrict__ P, float scale)
{
    __shared__ float red[4];
    const int row = blockIdx.x;
    const int tid = threadIdx.x;
    const int wave = tid >> 6;
    const float4* Sr = (const float4*)(S + (size_t)row * 4096);

    float4 x[4];
    #pragma unroll
    for (int i = 0; i < 4; ++i) x[i] = Sr[tid + i * 256];

    float mx = -3.402823466e+38f;
    #pragma unroll
    for (int i = 0; i < 4; ++i)
        mx = fmaxf(mx, fmaxf(fmaxf(x[i].x, x[i].y), fmaxf(x[i].z, x[i].w)));
    #pragma unroll
    for (int off = 32; off > 0; off >>= 1) mx = fmaxf(mx, __shfl_down(mx, off));
    if ((tid & 63) == 0) red[wave] = mx;
    __syncthreads();
    mx = fmaxf(fmaxf(red[0], red[1]), fmaxf(red[2], red[3]));
    __syncthreads();

    float sum = 0.0f;
    #pragma unroll
    for (int i = 0; i < 4; ++i) {
        x[i].x = __expf(x[i].x - mx);
        x[i].y = __expf(x[i].y - mx);
        x[i].z = __expf(x[i].z - mx);
        x[i].w = __expf(x[i].w - mx);
        sum += x[i].x + x[i].y + x[i].z + x[i].w;
    }
    #pragma unroll
    for (int off = 32; off > 0; off >>= 1) sum += __shfl_down(sum, off);
    if ((tid & 63) == 0) red[wave] = sum;
    __syncthreads();
    sum = red[0] + red[1] + red[2] + red[3];

    const float inv = scale / sum;
    f16x4* Pr = (f16x4*)(P + (size_t)row * 4096);
    #pragma unroll
    for (int i = 0; i < 4; ++i) {
        f16x4 h;
        h.x = (_Float16)(x[i].x * inv);
        h.y = (_Float16)(x[i].y * inv);
        h.z = (_Float16)(x[i].z * inv);
        h.w = (_Float16)(x[i].w * inv);
        Pr[tid + i * 256] = h;
    }
}

// convert two fp32 arrays to fp16 in one launch
__global__ __launch_bounds__(256) void cvt2_f32_f16(
    const float4* __restrict__ a, f16x4* __restrict__ da, int n4a,
    const float4* __restrict__ b, f16x4* __restrict__ db, int n4b)
{
    int i = blockIdx.x * 256 + threadIdx.x;
    const int stride = gridDim.x * 256;
    const int tot = n4a + n4b;
    for (; i < tot; i += stride) {
        const float4* s = (i < n4a) ? (a + i) : (b + (i - n4a));
        f16x4* d = (i < n4a) ? (da + i) : (db + (i - n4a));
        float4 v = *s;
        f16x4 h;
        h.x = (_Float16)v.x; h.y = (_Float16)v.y;
        h.z = (_Float16)v.z; h.w = (_Float16)v.w;
        *d = h;
    }
}

// Vt[c][r] = (f16) V[r][c];  V is rows x cols
__global__ __launch_bounds__(256) void transpose_cvt(
    const float* __restrict__ V, _Float16* __restrict__ Vt, int rows, int cols)
{
    __shared__ float tile[32][33];
    const int c0 = blockIdx.x * 32;
    const int r0 = blockIdx.y * 32;
    const int tx = threadIdx.x & 31;
    const int ty = threadIdx.x >> 5;   // 0..7
    #pragma unroll
    for (int i = 0; i < 4; ++i)
        tile[ty * 4 + i][tx] = V[(size_t)(r0 + ty * 4 + i) * cols + c0 + tx];
    __syncthreads();
    #pragma unroll
    for (int i = 0; i < 4; ++i)
        Vt[(size_t)(c0 + ty * 4 + i) * rows + r0 + tx] = (_Float16)tile[tx][ty * 4 + i];
}

// out = a + b
__global__ __launch_bounds__(256) void reduce2(
    const float4* __restrict__ a, const float4* __restrict__ b,
    float4* __restrict__ o, int n4)
{
    int i = blockIdx.x * 256 + threadIdx.x;
    const int stride = gridDim.x * 256;
    for (; i < n4; i += stride) {
        float4 u = a[i], v = b[i];
        float4 w;
        w.x = u.x + v.x; w.y = u.y + v.y; w.z = u.z + v.z; w.w = u.w + v.w;
        o[i] = w;
    }
}

// out = a + b + c + d
__global__ __launch_bounds__(256) void reduce4(
    const float4* __restrict__ a, const float4* __restrict__ b,
    const float4* __restrict__ c, const float4* __restrict__ d,
    float4* __restrict__ o, int n4)
{
    int i = blockIdx.x * 256 + threadIdx.x;
    const int stride = gridDim.x * 256;
    for (; i < n4; i += stride) {
        float4 u = a[i], v = b[i], x = c[i], y = d[i];
        float4 w;
        w.x = (u.x + v.x) + (x.x + y.x);
        w.y = (u.y + v.y) + (x.y + y.y);
        w.z = (u.z + v.z) + (x.z + y.z);
        w.w = (u.w + v.w) + (x.w + y.w);
        o[i] = w;
    }
}

extern "C" void kernel_launch(void* const* d_in, const int* in_sizes, int n_in,
                              void* d_out, int out_size, void* d_ws, size_t ws_size,
                              hipStream_t stream) {
    const float* Q = (const float*)d_in[0];
    const float* K = (const float*)d_in[1];
    const float* V = (const float*)d_in[2];
    float* out = (float*)d_out;

    const int n = 4096, m = 4096, d = 1024, vdim = 1024;
    const float scale = 0.03125f;  // 1024^-0.5

    char* w = (char*)d_ws;
    _Float16* Qh = (_Float16*)w;                        // 8 MB
    _Float16* Kh = (_Float16*)(w + (8u << 20));         // 8 MB
    _Float16* Vt = (_Float16*)(w + (16u << 20));        // 8 MB
    char* rest = w + (24u << 20);
    size_t avail = ws_size > (24u << 20) ? ws_size - (24u << 20) : 0;

    int nc = 128;
    if      ((size_t)4096 * m * 6 <= avail) nc = 4096;
    else if ((size_t)2048 * m * 6 <= avail) nc = 2048;
    else if ((size_t)1024 * m * 6 <= avail) nc = 1024;
    else if ((size_t)512  * m * 6 <= avail) nc = 512;
    else if ((size_t)256  * m * 6 <= avail) nc = 256;

    float*    S = (float*)rest;                            // nc*m*4
    _Float16* P = (_Float16*)(rest + (size_t)nc * m * 4);  // nc*m*2
    float* part = S;  // split-K partials reuse S (dead after softmax)

    cvt2_f32_f16<<<dim3(2048), dim3(256), 0, stream>>>(
        (const float4*)Q, (f16x4*)Qh, n * d / 4,
        (const float4*)K, (f16x4*)Kh, m * d / 4);
    transpose_cvt<<<dim3(vdim / 32, m / 32), dim3(256), 0, stream>>>(V, Vt, m, vdim);

    if (nc >= 256) {
        for (int r0 = 0; r0 < n; r0 += nc) {
            // S = Qc * Kh^T   [nc x m], K-dim = d
            gemm_bt256<<<dim3(m / 256, nc / 256, 1), dim3(512), 0, stream>>>(
                Qh + (size_t)r0 * d, Kh, S, nc, m, d, d);
            softmax_rows<<<dim3(nc), dim3(256), 0, stream>>>(S, P, scale);
            // part[z] = P[:, z*1024...] * Vt slice, z = 0..3 (split-K=4)
            gemm_bt256<<<dim3(vdim / 256, nc / 256, 4), dim3(512), 0, stream>>>(
                P, Vt, part, nc, vdim, m, m / 4);
            reduce4<<<dim3(1024), dim3(256), 0, stream>>>(
                (const float4*)part,
                (const float4*)(part + (size_t)nc * vdim),
                (const float4*)(part + (size_t)2 * nc * vdim),
                (const float4*)(part + (size_t)3 * nc * vdim),
                (float4*)(out + (size_t)r0 * vdim), nc * vdim / 4);
        }
    } else {
        // tiny-workspace fallback: verified 128-tile path
        for (int r0 = 0; r0 < n; r0 += nc) {
            gemm_bt<<<dim3(m / 128, nc / 128, 1), dim3(256), 0, stream>>>(
                Qh + (size_t)r0 * d, Kh, S, nc, m, d, d);
            softmax_rows<<<dim3(nc), dim3(256), 0, stream>>>(S, P, scale);
            gemm_bt<<<dim3(vdim / 128, nc / 128, 2), dim3(256), 0, stream>>>(
                P, Vt, part, nc, vdim, m, m / 2);
            reduce2<<<dim3(1024), dim3(256), 0, stream>>>(
                (const float4*)part, (const float4*)(part + (size_t)nc * vdim),
                (float4*)(out + (size_t)r0 * vdim), nc * vdim / 4);
        }
    }
}

// Round 7
// 189.462 us; speedup vs baseline: 1.0762x; 1.0762x over previous
//
#include <hip/hip_runtime.h>
#include <hip/hip_bf16.h>

typedef _Float16 f16x8 __attribute__((ext_vector_type(8)));
typedef _Float16 f16x4 __attribute__((ext_vector_type(4)));
typedef float f32x4 __attribute__((ext_vector_type(4)));

__device__ __forceinline__ void async_ld16(_Float16* lds, const _Float16* g) {
    __builtin_amdgcn_global_load_lds(
        (const __attribute__((address_space(1))) void*)g,
        (__attribute__((address_space(3))) void*)lds, 16, 0, 0);
}

#define VMCNT(n) asm volatile("s_waitcnt vmcnt(" #n ")" ::: "memory")
#define LGKMCNT0 asm volatile("s_waitcnt lgkmcnt(0)" ::: "memory")
#define BAR() __builtin_amdgcn_s_barrier()

// ============================================================================
// 256x256-tile 8-phase pipelined GEMM:  C[M,N] = A[M,K] * B[N,K]^T (f16->f32
// or f16 out when halfOut). R5 schedule (best measured: 44.8 us, 0 bank
// conflicts). 8 waves (2M x 4N), fragment map (R4-verified):
//   row = ms*128 + m*32 + wm*16 + (quad*4+e),  col = ns*128 + nn*64 + wn*16 + l16
// BK=64, LDS 128 KB, XOR chunk swizzle. Per K-tile: 4 phases, each
//   { ds_read quadrant | STAGE 1 half-tile | BAR | lgkmcnt(0) |
//     setprio(1) 16 MFMA setprio(0) | BAR }, vmcnt(6) once per K-tile.
// Bijective XCD remap (m204). Split-K over decoded z.
// ============================================================================
__global__ __launch_bounds__(512, 2) void gemm_bt256(
    const _Float16* __restrict__ A,
    const _Float16* __restrict__ B,
    void* __restrict__ Cv,
    int M, int N, int K, int Ks, int halfOut)
{
    __shared__ _Float16 Asm[2][256 * 64];
    __shared__ _Float16 Bsm[2][256 * 64];

    const int tid  = threadIdx.x;
    const int w    = tid >> 6;       // wave 0..7
    const int lane = tid & 63;
    const int l16  = lane & 15;
    const int quad = lane >> 4;
    const int wm   = w >> 2;         // 0..1  (M-group)
    const int wn   = w & 3;          // 0..3  (N-group)

    // ---- bijective XCD-chunked block remap (m204) ---------------------------
    const int gx = gridDim.x, gy = gridDim.y;
    const int total = gx * gy * (int)gridDim.z;
    int lid = (int)blockIdx.x + gx * ((int)blockIdx.y + gy * (int)blockIdx.z);
    {
        const int q = total >> 3, r = total & 7;
        const int xcd = lid & 7, i = lid >> 3;
        lid = (xcd < r ? xcd * (q + 1) : r * (q + 1) + (xcd - r) * q) + i;
    }
    const int bx = lid % gx;
    const int by = (lid / gx) % gy;
    const int bz = lid / (gx * gy);

    const int row0 = by * 256;
    const int col0 = bx * 256;

    const _Float16* Ab = A + (size_t)row0 * K + (size_t)bz * Ks;
    const _Float16* Bb = B + (size_t)col0 * K + (size_t)bz * Ks;

    // ---- staging addressing -------------------------------------------------
    // Half-tile = 128 rows x 64 halfs = 16 KB = 2 gload_lds per wave.
    // LDS dest linear: lane l -> row w*16 + (l>>3), chunk l&7.
    // Global source chunk pre-swizzled: lc = (l&7) ^ (row&7).
    const int lr = lane >> 3;
    const int lc = (lane & 7) ^ lr;
    const size_t soff  = (size_t)(w * 16 + lr) * K + lc * 8;
    const _Float16* pa = Ab + soff;
    const _Float16* pb = Bb + soff;
    const size_t jstep = (size_t)8 * K;    // +8 rows
    const size_t hstep = (size_t)128 * K;  // +1 half-tile

    auto STAGE = [&](_Float16* sm, const _Float16* gsrc, int h, int kcol) {
        _Float16* d = sm + h * 8192 + w * 1024;
        const _Float16* s = gsrc + (size_t)h * hstep + kcol;
        async_ld16(d,       s);
        async_ld16(d + 512, s + jstep);
    };

    // ---- fragment-read addressing (swizzled) --------------------------------
    // row&7 == l16&7; k-slice ks chunk = (ks*4+quad) ^ (row&7).
    const int abase = (wm * 16 + l16) * 64;
    const int bbase = (wn * 16 + l16) * 64;
    const int rs0   = ((quad)     ^ (l16 & 7)) * 8;   // k-slice 0
    const int rs1   = ((4 + quad) ^ (l16 & 7)) * 8;   // k-slice 1

#define READ_A(dst, msoff)                                                     \
    _Pragma("unroll")                                                          \
    for (int m_ = 0; m_ < 4; ++m_) {                                           \
        dst[m_][0] = *(const f16x8*)(abuf + (msoff) + m_ * 2048 + abase + rs0);\
        dst[m_][1] = *(const f16x8*)(abuf + (msoff) + m_ * 2048 + abase + rs1);\
    }
#define READ_B(dst, nsoff)                                                     \
    _Pragma("unroll")                                                          \
    for (int n_ = 0; n_ < 2; ++n_) {                                           \
        dst[n_][0] = *(const f16x8*)(bbuf + (nsoff) + n_ * 4096 + bbase + rs0);\
        dst[n_][1] = *(const f16x8*)(bbuf + (nsoff) + n_ * 4096 + bbase + rs1);\
    }
#define MFMA4x2(accrow, afrag, bfrag, bcol)                                    \
    _Pragma("unroll")                                                          \
    for (int m_ = 0; m_ < 4; ++m_)                                             \
      _Pragma("unroll")                                                        \
      for (int n_ = 0; n_ < 2; ++n_) {                                         \
        acc[(accrow) + m_][(bcol) + n_] =                                      \
            __builtin_amdgcn_mfma_f32_16x16x32_f16(                            \
                afrag[m_][0], bfrag[n_][0], acc[(accrow) + m_][(bcol) + n_],   \
                0, 0, 0);                                                      \
        acc[(accrow) + m_][(bcol) + n_] =                                      \
            __builtin_amdgcn_mfma_f32_16x16x32_f16(                            \
                afrag[m_][1], bfrag[n_][1], acc[(accrow) + m_][(bcol) + n_],   \
                0, 0, 0);                                                      \
      }

    f32x4 acc[8][4] = {};
    const int NT = Ks >> 6;   // K-tiles of 64

    // ---- prologue: kt0 fully + first 3 half-tiles of kt1 --------------------
    STAGE(&Asm[0][0], pa, 0, 0);
    STAGE(&Bsm[0][0], pb, 0, 0);
    STAGE(&Bsm[0][0], pb, 1, 0);
    STAGE(&Asm[0][0], pa, 1, 0);
    if (NT > 1) {
        STAGE(&Asm[1][0], pa, 0, 64);
        STAGE(&Bsm[1][0], pb, 0, 64);
        STAGE(&Bsm[1][0], pb, 1, 64);
        VMCNT(6);              // oldest 8 loads (= all of kt0) landed
    } else {
        VMCNT(0);
    }
    BAR();

    for (int t = 0; t < NT; ++t) {
        const int buf = t & 1;
        const _Float16* abuf = &Asm[buf][0];
        const _Float16* bbuf = &Bsm[buf][0];
        _Float16* const acur = &Asm[buf][0];        // kt t+2 lands here
        _Float16* const bcur = &Bsm[buf][0];
        _Float16* const anxt = &Asm[buf ^ 1][0];    // kt t+1 A.h1

        f16x8 alo[4][2], ahi[4][2], blo[2][2], bhi[2][2];

        // ---- phase 1: quadrant (ms=0, ns=0); reads A.h0 + B.h0 -------------
        READ_A(alo, 0);
        READ_B(blo, 0);
        if (t + 1 < NT) STAGE(anxt, pa, 1, (t + 1) * 64);
        BAR();
        LGKMCNT0;
        __builtin_amdgcn_s_setprio(1);
        MFMA4x2(0, alo, blo, 0);
        __builtin_amdgcn_s_setprio(0);
        BAR();

        // ---- phase 2: quadrant (ms=0, ns=1); A.h0 window closed -> refill --
        READ_B(bhi, 8192);
        if (t + 2 < NT) STAGE(acur, pa, 0, (t + 2) * 64);
        BAR();
        LGKMCNT0;
        __builtin_amdgcn_s_setprio(1);
        MFMA4x2(0, alo, bhi, 2);
        __builtin_amdgcn_s_setprio(0);
        BAR();

        // ---- phase 3: quadrant (ms=1, ns=1); B.h0 window closed -> refill --
        READ_A(ahi, 8192);
        if (t + 2 < NT) STAGE(bcur, pb, 0, (t + 2) * 64);
        BAR();
        LGKMCNT0;
        __builtin_amdgcn_s_setprio(1);
        MFMA4x2(4, ahi, bhi, 2);
        __builtin_amdgcn_s_setprio(0);
        BAR();

        // ---- phase 4: quadrant (ms=1, ns=0); B.h1 closed -> refill; vmcnt --
        if (t + 2 < NT) STAGE(bcur, pb, 1, (t + 2) * 64);
        BAR();
        __builtin_amdgcn_s_setprio(1);
        MFMA4x2(4, ahi, blo, 0);
        __builtin_amdgcn_s_setprio(0);
        if (t + 2 < NT) { VMCNT(6); } else { VMCNT(0); }  // kt t+1 landed
        BAR();
    }

    // ---- epilogue: C/D layout col = l16, row = quad*4 + reg ----------------
    if (halfOut) {
        _Float16* Ch = (_Float16*)Cv + (size_t)bz * ((size_t)M * N);
        #pragma unroll
        for (int i = 0; i < 8; ++i) {
            const int ms = i >> 2, m = i & 3;
            const int gr = row0 + ms * 128 + m * 32 + wm * 16 + quad * 4;
            #pragma unroll
            for (int j = 0; j < 4; ++j) {
                const int ns = j >> 1, nn = j & 1;
                const int gc = col0 + ns * 128 + nn * 64 + wn * 16 + l16;
                const f32x4 v = acc[i][j];
                #pragma unroll
                for (int e = 0; e < 4; ++e)
                    Ch[(size_t)(gr + e) * N + gc] = (_Float16)v[e];
            }
        }
    } else {
        float* Cb = (float*)Cv + (size_t)bz * ((size_t)M * N);
        #pragma unroll
        for (int i = 0; i < 8; ++i) {
            const int ms = i >> 2, m = i & 3;
            const int gr = row0 + ms * 128 + m * 32 + wm * 16 + quad * 4;
            #pragma unroll
            for (int j = 0; j < 4; ++j) {
                const int ns = j >> 1, nn = j & 1;
                const int gc = col0 + ns * 128 + nn * 64 + wn * 16 + l16;
                const f32x4 v = acc[i][j];
                #pragma unroll
                for (int e = 0; e < 4; ++e)
                    Cb[(size_t)(gr + e) * N + gc] = v[e];
            }
        }
    }
#undef READ_A
#undef READ_B
#undef MFMA4x2
}

// ============================================================================
// Fallback 128x128 GEMM (verified passing) for tiny-workspace nc=128 path.
// ============================================================================
__global__ __launch_bounds__(256) void gemm_bt(
    const _Float16* __restrict__ A,
    const _Float16* __restrict__ B,
    float* __restrict__ C,
    int M, int N, int K, int Ks)
{
    __shared__ _Float16 At[2][128 * 32];
    __shared__ _Float16 Bt[2][128 * 32];

    const int tid  = threadIdx.x;
    const int wave = tid >> 6;
    const int lane = tid & 63;

    int gx = gridDim.x, gy = gridDim.y;
    int bx = blockIdx.x, by = blockIdx.y;
    if (((gx & 7) == 0) && ((gy & 7) == 0)) {
        const int bid    = bx + gx * by;
        const int ntx    = gx >> 3;
        const int sid    = bid >> 6;
        const int within = bid & 63;
        const int sx = sid % ntx;
        const int sy = sid / ntx;
        bx = (sx << 3) + (within & 7);
        by = (sy << 3) + (within >> 3);
    }
    const int row0 = by * 128;
    const int col0 = bx * 128;

    const int wr = (wave >> 1) * 64;
    const int wc = (wave & 1) * 64;
    const int quad = lane >> 4;
    const int l16  = lane & 15;

    f32x4 acc[4][4] = {};

    const int srow  = lane >> 2;
    const int skoff = (lane & 3) * 8;
    const size_t K64 = (size_t)64 * K;

    const _Float16* Ab = A + (size_t)row0 * K + (size_t)blockIdx.z * Ks;
    const _Float16* Bb = B + (size_t)col0 * K + (size_t)blockIdx.z * Ks;
    float* Cb = C + (size_t)blockIdx.z * M * N;

    const _Float16* pa = Ab + (size_t)(wave * 16 + srow) * K + skoff;
    const _Float16* pb = Bb + (size_t)(wave * 16 + srow) * K + skoff;

    async_ld16(At[0] + wave * 512,       pa);
    async_ld16(At[0] + (wave + 4) * 512, pa + K64);
    async_ld16(Bt[0] + wave * 512,       pb);
    async_ld16(Bt[0] + (wave + 4) * 512, pb + K64);
    __syncthreads();

    int cur = 0;
    for (int k0 = 0; k0 < Ks; k0 += 32) {
        const int nxt = cur ^ 1;
        if (k0 + 32 < Ks) {
            const _Float16* qa = pa + k0 + 32;
            const _Float16* qb = pb + k0 + 32;
            async_ld16(At[nxt] + wave * 512,       qa);
            async_ld16(At[nxt] + (wave + 4) * 512, qa + K64);
            async_ld16(Bt[nxt] + wave * 512,       qb);
            async_ld16(Bt[nxt] + (wave + 4) * 512, qb + K64);
        }

        f16x8 af[4], bf[4];
        #pragma unroll
        for (int r = 0; r < 4; ++r)
            af[r] = *(const f16x8*)&At[cur][(wr + r * 16 + l16) * 32 + quad * 8];
        #pragma unroll
        for (int c = 0; c < 4; ++c)
            bf[c] = *(const f16x8*)&Bt[cur][(wc + c * 16 + l16) * 32 + quad * 8];

        #pragma unroll
        for (int r = 0; r < 4; ++r)
            #pragma unroll
            for (int c = 0; c < 4; ++c)
                acc[r][c] = __builtin_amdgcn_mfma_f32_16x16x32_f16(af[r], bf[c], acc[r][c], 0, 0, 0);

        __syncthreads();
        cur = nxt;
    }

    #pragma unroll
    for (int r = 0; r < 4; ++r) {
        const int growb = row0 + wr + r * 16 + quad * 4;
        #pragma unroll
        for (int c = 0; c < 4; ++c) {
            const int gcol = col0 + wc + c * 16 + l16;
            #pragma unroll
            for (int i = 0; i < 4; ++i)
                Cb[(size_t)(growb + i) * N + gcol] = acc[r][c][i];
        }
    }
}

// one block (256 thr) per row of S [rows x 4096]; P = softmax(S)*scale in fp16
__global__ __launch_bounds__(256) void softmax_rows(
    const float* __restrict__ S, _Float16* __restrict__ P, float scale)
{
    __shared__ float red[4];
    const int row = blockIdx.x;
    const int tid = threadIdx.x;
    const int wave = tid >> 6;
    const float4* Sr = (const float4*)(S + (size_t)row * 4096);

    float4 x[4];
    #pragma unroll
    for (int i = 0; i < 4; ++i) x[i] = Sr[tid + i * 256];

    float mx = -3.402823466e+38f;
    #pragma unroll
    for (int i = 0; i < 4; ++i)
        mx = fmaxf(mx, fmaxf(fmaxf(x[i].x, x[i].y), fmaxf(x[i].z, x[i].w)));
    #pragma unroll
    for (int off = 32; off > 0; off >>= 1) mx = fmaxf(mx, __shfl_down(mx, off));
    if ((tid & 63) == 0) red[wave] = mx;
    __syncthreads();
    mx = fmaxf(fmaxf(red[0], red[1]), fmaxf(red[2], red[3]));
    __syncthreads();

    float sum = 0.0f;
    #pragma unroll
    for (int i = 0; i < 4; ++i) {
        x[i].x = __expf(x[i].x - mx);
        x[i].y = __expf(x[i].y - mx);
        x[i].z = __expf(x[i].z - mx);
        x[i].w = __expf(x[i].w - mx);
        sum += x[i].x + x[i].y + x[i].z + x[i].w;
    }
    #pragma unroll
    for (int off = 32; off > 0; off >>= 1) sum += __shfl_down(sum, off);
    if ((tid & 63) == 0) red[wave] = sum;
    __syncthreads();
    sum = red[0] + red[1] + red[2] + red[3];

    const float inv = scale / sum;
    f16x4* Pr = (f16x4*)(P + (size_t)row * 4096);
    #pragma unroll
    for (int i = 0; i < 4; ++i) {
        f16x4 h;
        h.x = (_Float16)(x[i].x * inv);
        h.y = (_Float16)(x[i].y * inv);
        h.z = (_Float16)(x[i].z * inv);
        h.w = (_Float16)(x[i].w * inv);
        Pr[tid + i * 256] = h;
    }
}

// ============================================================================
// prep: one launch doing (by==0) f32->f16 convert of Q and K, and
// (by==1) Vt[c][r] = (f16) V[r][c]  (32x32 tiles, rows=4096, cols=1024).
// Branch is block-uniform so the __syncthreads in the transpose arm is legal.
// ============================================================================
__global__ __launch_bounds__(256) void prep(
    const float4* __restrict__ Qs, f16x4* __restrict__ Qh, int n4q,
    const float4* __restrict__ Ks, f16x4* __restrict__ Kh, int n4k,
    const float* __restrict__ V, _Float16* __restrict__ Vt, int rows, int cols)
{
    __shared__ float tile[32][33];
    if (blockIdx.y == 0) {
        int i = blockIdx.x * 256 + threadIdx.x;
        const int stride = gridDim.x * 256;
        const int tot = n4q + n4k;
        for (; i < tot; i += stride) {
            const float4* s = (i < n4q) ? (Qs + i) : (Ks + (i - n4q));
            f16x4* dst = (i < n4q) ? (Qh + i) : (Kh + (i - n4q));
            float4 v = *s;
            f16x4 h;
            h.x = (_Float16)v.x; h.y = (_Float16)v.y;
            h.z = (_Float16)v.z; h.w = (_Float16)v.w;
            *dst = h;
        }
    } else {
        const int cb = blockIdx.x & 31;   // cols/32 = 32
        const int rb = blockIdx.x >> 5;   // rows/32 = 128
        const int c0 = cb * 32;
        const int r0 = rb * 32;
        const int tx = threadIdx.x & 31;
        const int ty = threadIdx.x >> 5;  // 0..7
        #pragma unroll
        for (int i = 0; i < 4; ++i)
            tile[ty * 4 + i][tx] = V[(size_t)(r0 + ty * 4 + i) * cols + c0 + tx];
        __syncthreads();
        #pragma unroll
        for (int i = 0; i < 4; ++i)
            Vt[(size_t)(c0 + ty * 4 + i) * rows + r0 + tx] = (_Float16)tile[tx][ty * 4 + i];
    }
}

// legacy prep kernels kept for the tiny-workspace fallback path
__global__ __launch_bounds__(256) void cvt2_f32_f16(
    const float4* __restrict__ a, f16x4* __restrict__ da, int n4a,
    const float4* __restrict__ b, f16x4* __restrict__ db, int n4b)
{
    int i = blockIdx.x * 256 + threadIdx.x;
    const int stride = gridDim.x * 256;
    const int tot = n4a + n4b;
    for (; i < tot; i += stride) {
        const float4* s = (i < n4a) ? (a + i) : (b + (i - n4a));
        f16x4* d = (i < n4a) ? (da + i) : (db + (i - n4a));
        float4 v = *s;
        f16x4 h;
        h.x = (_Float16)v.x; h.y = (_Float16)v.y;
        h.z = (_Float16)v.z; h.w = (_Float16)v.w;
        *d = h;
    }
}

__global__ __launch_bounds__(256) void transpose_cvt(
    const float* __restrict__ V, _Float16* __restrict__ Vt, int rows, int cols)
{
    __shared__ float tile[32][33];
    const int c0 = blockIdx.x * 32;
    const int r0 = blockIdx.y * 32;
    const int tx = threadIdx.x & 31;
    const int ty = threadIdx.x >> 5;   // 0..7
    #pragma unroll
    for (int i = 0; i < 4; ++i)
        tile[ty * 4 + i][tx] = V[(size_t)(r0 + ty * 4 + i) * cols + c0 + tx];
    __syncthreads();
    #pragma unroll
    for (int i = 0; i < 4; ++i)
        Vt[(size_t)(c0 + ty * 4 + i) * rows + r0 + tx] = (_Float16)tile[tx][ty * 4 + i];
}

// out = a + b (f32 partials, fallback path)
__global__ __launch_bounds__(256) void reduce2(
    const float4* __restrict__ a, const float4* __restrict__ b,
    float4* __restrict__ o, int n4)
{
    int i = blockIdx.x * 256 + threadIdx.x;
    const int stride = gridDim.x * 256;
    for (; i < n4; i += stride) {
        float4 u = a[i], v = b[i];
        float4 w;
        w.x = u.x + v.x; w.y = u.y + v.y; w.z = u.z + v.z; w.w = u.w + v.w;
        o[i] = w;
    }
}

// out(f32) = a + b + c + d over f16 partial slabs; n8 = elements/8
__global__ __launch_bounds__(256) void reduce4h(
    const f16x8* __restrict__ a, const f16x8* __restrict__ b,
    const f16x8* __restrict__ c, const f16x8* __restrict__ d,
    float4* __restrict__ o, int n8)
{
    int i = blockIdx.x * 256 + threadIdx.x;
    const int stride = gridDim.x * 256;
    for (; i < n8; i += stride) {
        f16x8 u = a[i], v = b[i], x = c[i], y = d[i];
        float s[8];
        #pragma unroll
        for (int e = 0; e < 8; ++e)
            s[e] = ((float)u[e] + (float)v[e]) + ((float)x[e] + (float)y[e]);
        float4 o0, o1;
        o0.x = s[0]; o0.y = s[1]; o0.z = s[2]; o0.w = s[3];
        o1.x = s[4]; o1.y = s[5]; o1.z = s[6]; o1.w = s[7];
        o[2 * i]     = o0;
        o[2 * i + 1] = o1;
    }
}

extern "C" void kernel_launch(void* const* d_in, const int* in_sizes, int n_in,
                              void* d_out, int out_size, void* d_ws, size_t ws_size,
                              hipStream_t stream) {
    const float* Q = (const float*)d_in[0];
    const float* K = (const float*)d_in[1];
    const float* V = (const float*)d_in[2];
    float* out = (float*)d_out;

    const int n = 4096, m = 4096, d = 1024, vdim = 1024;
    const float scale = 0.03125f;  // 1024^-0.5

    char* w = (char*)d_ws;
    _Float16* Qh = (_Float16*)w;                        // 8 MB
    _Float16* Kh = (_Float16*)(w + (8u << 20));         // 8 MB
    _Float16* Vt = (_Float16*)(w + (16u << 20));        // 8 MB
    char* rest = w + (24u << 20);
    size_t avail = ws_size > (24u << 20) ? ws_size - (24u << 20) : 0;

    int nc = 128;
    if      ((size_t)4096 * m * 6 <= avail) nc = 4096;
    else if ((size_t)2048 * m * 6 <= avail) nc = 2048;
    else if ((size_t)1024 * m * 6 <= avail) nc = 1024;
    else if ((size_t)512  * m * 6 <= avail) nc = 512;
    else if ((size_t)256  * m * 6 <= avail) nc = 256;

    float*    S = (float*)rest;                            // nc*m*4
    _Float16* P = (_Float16*)(rest + (size_t)nc * m * 4);  // nc*m*2
    // split-K partials: f16 slabs reuse S region (dead after softmax);
    // 4 * nc*vdim * 2B = nc*vdim*8 <= nc*m*4 since vdim*2 <= m.
    _Float16* partH = (_Float16*)rest;

    if (nc >= 256) {
        prep<<<dim3(4096, 2), dim3(256), 0, stream>>>(
            (const float4*)Q, (f16x4*)Qh, n * d / 4,
            (const float4*)K, (f16x4*)Kh, m * d / 4,
            V, Vt, m, vdim);
        for (int r0 = 0; r0 < n; r0 += nc) {
            // S = Qc * Kh^T   [nc x m], K-dim = d, f32 out
            gemm_bt256<<<dim3(m / 256, nc / 256, 1), dim3(512), 0, stream>>>(
                Qh + (size_t)r0 * d, Kh, S, nc, m, d, d, 0);
            softmax_rows<<<dim3(nc), dim3(256), 0, stream>>>(S, P, scale);
            // partH[z] = P[:, z*1024...] * Vt slice, z = 0..3, f16 out
            gemm_bt256<<<dim3(vdim / 256, nc / 256, 4), dim3(512), 0, stream>>>(
                P, Vt, partH, nc, vdim, m, m / 4, 1);
            reduce4h<<<dim3(1024), dim3(256), 0, stream>>>(
                (const f16x8*)partH,
                (const f16x8*)(partH + (size_t)nc * vdim),
                (const f16x8*)(partH + (size_t)2 * nc * vdim),
                (const f16x8*)(partH + (size_t)3 * nc * vdim),
                (float4*)(out + (size_t)r0 * vdim), nc * vdim / 8);
        }
    } else {
        // tiny-workspace fallback: verified 128-tile path (f32 partials)
        float* part = S;
        cvt2_f32_f16<<<dim3(2048), dim3(256), 0, stream>>>(
            (const float4*)Q, (f16x4*)Qh, n * d / 4,
            (const float4*)K, (f16x4*)Kh, m * d / 4);
        transpose_cvt<<<dim3(vdim / 32, m / 32), dim3(256), 0, stream>>>(V, Vt, m, vdim);
        for (int r0 = 0; r0 < n; r0 += nc) {
            gemm_bt<<<dim3(m / 128, nc / 128, 1), dim3(256), 0, stream>>>(
                Qh + (size_t)r0 * d, Kh, S, nc, m, d, d);
            softmax_rows<<<dim3(nc), dim3(256), 0, stream>>>(S, P, scale);
            gemm_bt<<<dim3(vdim / 128, nc / 128, 2), dim3(256), 0, stream>>>(
                P, Vt, part, nc, vdim, m, m / 2);
            reduce2<<<dim3(1024), dim3(256), 0, stream>>>(
                (const float4*)part, (const float4*)(part + (size_t)nc * vdim),
                (float4*)(out + (size_t)r0 * vdim), nc * vdim / 4);
        }
    }
}